// Round 10
// baseline (85609.637 us; speedup 1.0000x reference)
//
#include <hip/hip_runtime.h>
#include <float.h>

constexpr int SEQ  = 128;   // sentence length T
constexpr int D    = 256;   // DIM / STATEDIM
constexpr int G    = 1024;  // 4*DIM gate width
constexpr int NREL = 26;    // REL_COUNT + 1
constexpr int NENT = 7;

typedef float v2f __attribute__((ext_vector_type(2)));

// ---------------------------------------------------------------------------
// Generic strided transpose: out[k*rows + i] = in[i*in_stride + in_off + k]
// ---------------------------------------------------------------------------
__global__ void k_trans(const float* __restrict__ in, float* __restrict__ out,
                        int rows, int cols, int in_stride, int in_off)
{
    int idx = blockIdx.x * 256 + threadIdx.x;
    if (idx >= rows * cols) return;
    int i = idx % rows;
    int k = idx / rows;
    out[idx] = in[(size_t)i * in_stride + in_off + k];
}

// ---------------------------------------------------------------------------
// xg[t][j] = bih[j] + bhh[j] + sum_k wordvector[text[t]][k] * Wih[j][k]
// ---------------------------------------------------------------------------
__global__ __launch_bounds__(1024) void k_xg(
    const int* __restrict__ text, const float* __restrict__ wv,
    const float* __restrict__ Wih, const float* __restrict__ bih,
    const float* __restrict__ bhh, float* __restrict__ xg)
{
    int t = blockIdx.x, j = threadIdx.x;
    const float* x  = wv + (size_t)text[t] * D;
    const float* wr = Wih + (size_t)j * D;
    float acc = bih[j] + bhh[j];
    for (int k = 0; k < D; ++k) acc += x[k] * wr[k];
    xg[t * G + j] = acc;
}

// ---------------------------------------------------------------------------
// Sequential LSTM, one block per direction (grid=2), 1024 threads.
// ---------------------------------------------------------------------------
__global__ __launch_bounds__(1024) void k_lstm(
    const float* __restrict__ xgF, const float* __restrict__ xgB,
    const float* __restrict__ WHTF, const float* __restrict__ WHTB,
    float* __restrict__ wordin)
{
    int dir = blockIdx.x;
    const float* xg  = dir ? xgB  : xgF;
    const float* WHT = dir ? WHTB : WHTF;
    __shared__ float h[D], c[D], g[G];
    int j = threadIdx.x;
    if (j < D) { h[j] = 0.f; c[j] = 0.f; }
    __syncthreads();
    for (int s = 0; s < SEQ; ++s) {
        int t = dir ? (SEQ - 1 - s) : s;
        float acc = xg[t * G + j];
        for (int k = 0; k < D; ++k) acc += WHT[k * G + j] * h[k];
        g[j] = acc;
        __syncthreads();
        if (j < D) {
            float si = 1.f / (1.f + expf(-g[j]));
            float sf = 1.f / (1.f + expf(-g[D + j]));
            float gg = tanhf(g[2 * D + j]);
            float so = 1.f / (1.f + expf(-g[3 * D + j]));
            float cn = sf * c[j] + si * gg;
            float hn = so * tanhf(cn);
            c[j] = cn; h[j] = hn;
            wordin[t * (2 * D) + dir * D + j] = hn;
        }
        __syncthreads();
    }
}

// ---------------------------------------------------------------------------
// Parallel precompute after LSTM (TW/BW per word, RV per relation, EV per ent)
// ---------------------------------------------------------------------------
__global__ __launch_bounds__(256) void k_prep2(
    const float* __restrict__ wordin,
    const float* __restrict__ WTWT, const float* __restrict__ WBWT,
    const float* __restrict__ WTRT, const float* __restrict__ WBET,
    const float* __restrict__ relvec, const float* __restrict__ entvec,
    const float* __restrict__ btv, const float* __restrict__ bbv,
    float* __restrict__ TW, float* __restrict__ BW,
    float* __restrict__ RV, float* __restrict__ EV)
{
    int b = blockIdx.x, i = threadIdx.x;
    if (b < SEQ) {
        const float* w = wordin + b * (2 * D);
        float a1 = btv[i], a2 = bbv[i];
        for (int j = 0; j < 2 * D; ++j) {
            float wv = w[j];
            a1 += wv * WTWT[j * D + i];
            a2 += wv * WBWT[j * D + i];
        }
        TW[b * D + i] = a1;
        BW[b * D + i] = a2;
    } else if (b < SEQ + NREL) {
        int r = b - SEQ;
        const float* x = relvec + r * D;
        float a = 0.f;
        for (int k = 0; k < D; ++k) a += x[k] * WTRT[k * D + i];
        RV[r * D + i] = a;
    } else {
        int e = b - SEQ - NREL;
        const float* x = entvec + e * D;
        float a = 0.f;
        for (int k = 0; k < D; ++k) a += x[k] * WBET[k * D + i];
        EV[e * D + i] = a;
    }
}

// ---------------------------------------------------------------------------
// M1T[j*D + i] = sum_k WBGT[k*D+i] * Wtt[k*D+j]   (M1 = Wb_target @ Wtt)
// ---------------------------------------------------------------------------
__global__ __launch_bounds__(256) void k_m1(
    const float* __restrict__ WBGT, const float* __restrict__ Wtt,
    float* __restrict__ M1T)
{
    int j = blockIdx.x, i = threadIdx.x;
    float a = 0.f;
    for (int k = 0; k < D; ++k) a = fmaf(WBGT[k * D + i], Wtt[k * D + j], a);
    M1T[j * D + i] = a;
}

// c1[i] = sum_k WBGT[k*D+i] * btt[k]
__global__ __launch_bounds__(256) void k_c1(
    const float* __restrict__ WBGT, const float* __restrict__ btt,
    float* __restrict__ c1)
{
    int i = threadIdx.x;
    float a = 0.f;
    for (int k = 0; k < D; ++k) a = fmaf(WBGT[k * D + i], btt[k], a);
    c1[i] = a;
}

// ---------------------------------------------------------------------------
// Packs for the 3-tier bot weight matvec (256 threads, thread i = output i):
//  reg tier  k=0..47   : WREG[i*48 + q]          = Wb[i][768 + q]
//  LDS tier  k=48..191 : f4 slot (w*36+j)*64+l   = Wb[w*64+l][768+48 + 4j+c]
//  L2 tier   k=192..255: f4 slot j*256 + i       = Wb[i][768+192 + 4j+c]
// ---------------------------------------------------------------------------
__global__ __launch_bounds__(256) void k_pack9r(
    const float* __restrict__ Wb, float* __restrict__ WREG)
{
    int e = blockIdx.x * 256 + threadIdx.x;      // 0..12287
    if (e >= 256 * 48) return;
    int i = e / 48, q = e % 48;
    WREG[e] = Wb[(size_t)i * (5 * D) + 3 * D + q];
}

__global__ __launch_bounds__(256) void k_pack9l(
    const float* __restrict__ Wb, float* __restrict__ WLDS)
{
    int f = blockIdx.x * 256 + threadIdx.x;      // 0..36863
    if (f >= 256 * 144) return;
    int f4 = f >> 2, c = f & 3;
    int l = f4 & 63, rest = f4 >> 6;
    int j = rest % 36, w = rest / 36;
    WLDS[f] = Wb[(size_t)(w * 64 + l) * (5 * D) + 3 * D + 48 + 4 * j + c];
}

__global__ __launch_bounds__(256) void k_pack9g(
    const float* __restrict__ Wb, float* __restrict__ WGL)
{
    int f = blockIdx.x * 256 + threadIdx.x;      // 0..16383
    if (f >= 256 * 64) return;
    int f4 = f >> 2, c = f & 3;
    int i = f4 & 255, j = f4 >> 8;
    WGL[f] = Wb[(size_t)i * (5 * D) + 3 * D + 192 + 4 * j + c];
}

// ---------------------------------------------------------------------------
// Full-k streamed matvec (top steps): Wcol = W^T[.. *D + i] (k-major, L2),
// x4 = LDS vector as float4 (broadcast reads). 4 independent chains.
// ---------------------------------------------------------------------------
__device__ inline float mv_full(const float* __restrict__ Wcol,
                                const float4* __restrict__ x4)
{
    float a0 = 0.f, a1 = 0.f, a2 = 0.f, a3 = 0.f;
    #pragma unroll 8
    for (int kk = 0; kk < 64; ++kk) {
        float4 xv = x4[kk];
        a0 = fmaf(Wcol[(4 * kk + 0) * D], xv.x, a0);
        a1 = fmaf(Wcol[(4 * kk + 1) * D], xv.y, a1);
        a2 = fmaf(Wcol[(4 * kk + 2) * D], xv.z, a2);
        a3 = fmaf(Wcol[(4 * kk + 3) * D], xv.w, a3);
    }
    return (a0 + a1) + (a2 + a3);
}

// ---------------------------------------------------------------------------
// Softmax + first-occurrence argmax over n values in lanes 0..n-1 of each
// W-lane group (reference-faithful: p = exp(l-max)/sum, argmax over p).
// ---------------------------------------------------------------------------
template<int W>
__device__ inline void grp_smax(float lv, int n, int lane, int& am, float& pm)
{
    float mx = lv;
    #pragma unroll
    for (int off = W / 2; off; off >>= 1) mx = fmaxf(mx, __shfl_xor(mx, off));
    float e  = (lane < n) ? expf(lv - mx) : 0.f;
    float se = e;
    #pragma unroll
    for (int off = W / 2; off; off >>= 1) se += __shfl_xor(se, off);
    float p  = (lane < n) ? (e / se) : -1.f;
    float q  = p;
    #pragma unroll
    for (int off = W / 2; off; off >>= 1) q = fmaxf(q, __shfl_xor(q, off));
    unsigned long long mask = __ballot(p == q);
    am = __ffsll((long long)mask) - 1;
    pm = q;
}

// FMA helpers: one float4 pair into two v2f accumulators
#define FMA_AB(Wv, Xv)                                                        \
    { float4 xx_ = (Xv);                                                      \
      A0 = __builtin_elementwise_fma((v2f){(Wv).x, (Wv).y},                   \
                                     (v2f){xx_.x, xx_.y}, A0);                \
      A1 = __builtin_elementwise_fma((v2f){(Wv).z, (Wv).w},                   \
                                     (v2f){xx_.z, xx_.w}, A1); }
#define FMA_CD(Wv, Xv)                                                        \
    { float4 xx_ = (Xv);                                                      \
      A2 = __builtin_elementwise_fma((v2f){(Wv).x, (Wv).y},                   \
                                     (v2f){xx_.x, xx_.y}, A2);                \
      A3 = __builtin_elementwise_fma((v2f){(Wv).z, (Wv).w},                   \
                                     (v2f){xx_.z, xx_.w}, A3); }

// one LDS weight chunk: 4 f4 weights x 4 f4 x-broadcast, then a fence
#define LDS_CHUNK(c)                                                          \
    { float4 la = wbase[(4 * (c) + 0) * 64], lb = wbase[(4 * (c) + 1) * 64],  \
             lc = wbase[(4 * (c) + 2) * 64], ld = wbase[(4 * (c) + 3) * 64];  \
      FMA_AB(la, xb[12 + 4 * (c) + 0]) FMA_CD(lb, xb[12 + 4 * (c) + 1])       \
      FMA_AB(lc, xb[12 + 4 * (c) + 2]) FMA_CD(ld, xb[12 + 4 * (c) + 3])       \
      __builtin_amdgcn_sched_barrier(0); }

#define GBATCH(b)                                                             \
    ga = glv[(4 * (b) + 0) * 256]; gb = glv[(4 * (b) + 1) * 256];             \
    gc = glv[(4 * (b) + 2) * 256]; gd = glv[(4 * (b) + 3) * 256];

#define GFMA(b)                                                               \
    FMA_AB(ga, xb[48 + 4 * (b) + 0]) FMA_CD(gb, xb[48 + 4 * (b) + 1])         \
    FMA_AB(gc, xb[48 + 4 * (b) + 2]) FMA_CD(gd, xb[48 + 4 * (b) + 3])         \
    __builtin_amdgcn_sched_barrier(0);

// ---------------------------------------------------------------------------
// Sequential main kernel: 1 block, 256 threads = 4 waves = 1 wave/SIMD.
// R9 post-mortem: grant at 256 thr is ~148 VGPRs; R9 demand ~190 -> ~12
// weight-f4 reload-spilled per step (FETCH 50 KB/step, the exposed-latency
// bottleneck). This round the design demand is ~140: 12 f4 weights in regs,
// 36 f4 in LDS (144 KB, conflict-free), 16 f4 re-streamed from L2 per step
// (asm-pinned, issued in 4 batches two chunks ahead). ev in registers, Esh
// dropped. Fenced 4-f4 chunks cap live transients.
// ---------------------------------------------------------------------------
__global__ __launch_bounds__(256)
__attribute__((amdgpu_waves_per_eu(1)))
void k_main8(
    const float* __restrict__ TW,   const float* __restrict__ BW,
    const float* __restrict__ RV,   const float* __restrict__ EV,
    const float* __restrict__ WTMT, const float* __restrict__ WTBT,
    const float* __restrict__ WBTT, const float* __restrict__ M1T,
    const float* __restrict__ c1v,  const float* __restrict__ WREG,
    const float* __restrict__ WLDS, const float* __restrict__ WGL,
    const float* __restrict__ Wp,   const float* __restrict__ bp,
    const float* __restrict__ Wpl,  const float* __restrict__ bpl,
    const float* __restrict__ btb,  const float* __restrict__ bbt,
    float* __restrict__ out)
{
    const int tid  = threadIdx.x;     // = output index i
    const int lane = tid & 63;
    const int w8   = tid >> 6;        // wave id 0..3

    __shared__ __align__(16) float wlds[256 * 144];    // 144 KB weight tier
    __shared__ __align__(16) float xbuf[2][D];
    __shared__ __align__(16) float mem[D], outv[D];
    __shared__ __align__(16) float WrSh[NENT * D];
    __shared__ float lpartT[4][32];
    __shared__ float lpartB[2][4][8];
    __shared__ float brSh[8];

    // stage LDS weight tier (pre-packed in exact LDS layout)
    {
        const float4* g4 = reinterpret_cast<const float4*>(WLDS);
        float4* w4 = reinterpret_cast<float4*>(wlds);
        #pragma unroll
        for (int it = 0; it < 36; ++it) w4[tid + it * 256] = g4[tid + it * 256];
    }
    mem[tid] = 0.f;

    // register tier: 12 NAMED float4 (48 VGPRs)
    const float4* r4 = reinterpret_cast<const float4*>(WREG) + tid * 12;
    float4 wr0 = r4[0],  wr1 = r4[1],  wr2 = r4[2],  wr3 = r4[3];
    float4 wr4 = r4[4],  wr5 = r4[5],  wr6 = r4[6],  wr7 = r4[7];
    float4 wr8 = r4[8],  wr9 = r4[9],  wr10 = r4[10], wr11 = r4[11];

    // loop-invariant entity columns in registers (7 regs)
    float ev0 = EV[0 * D + tid], ev1 = EV[1 * D + tid], ev2 = EV[2 * D + tid],
          ev3 = EV[3 * D + tid], ev4 = EV[4 * D + tid], ev5 = EV[5 * D + tid],
          ev6 = EV[6 * D + tid];

    __syncthreads();

    const float4* wbase =
        reinterpret_cast<const float4*>(wlds) + (size_t)w8 * (36 * 64) + lane;
    const float4* gl = reinterpret_cast<const float4*>(WGL) + tid;

    const float* WTMc = WTMT + tid;
    const float* WTBc = WTBT + tid;
    const float* WBTc = WBTT + tid;
    const float* M1c  = M1T  + tid;

    int rel = 0;

    for (int t = 0; t < SEQ; ++t) {
        // ---- top step: outp = tanh(TW[t] + RV[rel] + Wt_m @ mem) ----
        float a = mv_full(WTMc, reinterpret_cast<const float4*>(mem));
        float outp = tanhf(a + TW[t * D + tid] + RV[rel * D + tid]);
        outv[tid] = outp;
        for (int r = 0; r < NREL; ++r) {
            float pp = outp * Wp[r * D + tid];
            #pragma unroll
            for (int off = 32; off; off >>= 1) pp += __shfl_xor(pp, off);
            if (lane == 0) lpartT[w8][r] = pp;
        }
        __syncthreads();
        float lv = -FLT_MAX;
        if (lane < NREL)
            lv = lpartT[0][lane] + lpartT[1][lane] + lpartT[2][lane] +
                 lpartT[3][lane] + bp[lane];
        int am; float pm;
        grp_smax<32>(lv, NREL, lane, am, pm);
        if (tid == 0) { out[t] = (float)am; out[SEQ + t] = pm; }
        const int action = am;   // wave-uniform

        if (action > 0) {
            rel = action;
            // memb0 = Wtb@outp + btb ;  btm = M1@outp + c1  (tgt folded away)
            float bs = mv_full(WTBc, reinterpret_cast<const float4*>(outv));
            float cs = mv_full(M1c,  reinterpret_cast<const float4*>(outv));
            const size_t wb0 = (size_t)(action - 1) * NENT * D;
            for (int k = tid; k < NENT * D; k += 256) WrSh[k] = Wpl[wb0 + k];
            if (tid < NENT) brSh[tid] = bpl[(action - 1) * NENT + tid];
            float btm = cs + c1v[tid];
            xbuf[0][tid] = bs + btb[tid];
            float bwc = BW[tid];            // prefetch BW row 0
            __syncthreads();

            int p = 0, ab = 0;
            for (int s = 0; s < SEQ; ++s) {
                const float4* xb = reinterpret_cast<const float4*>(xbuf[p]);
                const float4* glv = gl;
                asm volatile("" : "+v"(glv));   // force per-step L2 reload

                v2f A0 = {0.f, 0.f}, A1 = {0.f, 0.f},
                    A2 = {0.f, 0.f}, A3 = {0.f, 0.f};
                float4 ga, gb, gc, gd;
                // reg tier k=0..47, fenced 4-f4 chunks
                FMA_AB(wr0, xb[0]) FMA_CD(wr1, xb[1])
                FMA_AB(wr2, xb[2]) FMA_CD(wr3, xb[3])
                __builtin_amdgcn_sched_barrier(0);
                FMA_AB(wr4, xb[4]) FMA_CD(wr5, xb[5])
                FMA_AB(wr6, xb[6]) FMA_CD(wr7, xb[7])
                __builtin_amdgcn_sched_barrier(0);
                FMA_AB(wr8, xb[8])  FMA_CD(wr9, xb[9])
                FMA_AB(wr10, xb[10]) FMA_CD(wr11, xb[11])
                __builtin_amdgcn_sched_barrier(0);
                // LDS tier k=48..191 (9 chunks), L2 tier k=192..255
                // issued in 4 batches, each 2 chunks ahead of its use
                GBATCH(0)
                LDS_CHUNK(0) LDS_CHUNK(1)
                GFMA(0)
                GBATCH(1)
                LDS_CHUNK(2) LDS_CHUNK(3)
                GFMA(1)
                GBATCH(2)
                LDS_CHUNK(4) LDS_CHUNK(5)
                GFMA(2)
                GBATCH(3)
                LDS_CHUNK(6) LDS_CHUNK(7)
                GFMA(3)
                LDS_CHUNK(8)
                v2f AS = (A0 + A1) + (A2 + A3);
                float ms = AS.x + AS.y;

                float ev = (ab == 0) ? ev0 : (ab == 1) ? ev1 :
                           (ab == 2) ? ev2 : (ab == 3) ? ev3 :
                           (ab == 4) ? ev4 : (ab == 5) ? ev5 : ev6;
                float ob = tanhf(ms + bwc + ev + btm);
                xbuf[p ^ 1][tid] = ob;
                #pragma unroll
                for (int r = 0; r < NENT; ++r) {
                    float pp = ob * WrSh[r * D + tid];
                    #pragma unroll
                    for (int off = 32; off; off >>= 1)
                        pp += __shfl_xor(pp, off);
                    if (lane == 0) lpartB[p][w8][r] = pp;
                }
                __syncthreads();                      // the ONE barrier/step
                float lv2 = -FLT_MAX;
                if (lane < NENT)
                    lv2 = lpartB[p][0][lane] + lpartB[p][1][lane] +
                          lpartB[p][2][lane] + lpartB[p][3][lane] + brSh[lane];
                int am2; float pm2;
                grp_smax<8>(lv2, NENT, lane, am2, pm2);
                if (tid == 0) {
                    out[2 * SEQ + t * SEQ + s] = (float)am2;
                    out[2 * SEQ + SEQ * SEQ + t * SEQ + s] = pm2;
                }
                ab = am2;
                int sn = (s + 1 < SEQ) ? s + 1 : s;
                bwc = BW[sn * D + tid];               // prefetch next row
                p ^= 1;
            }
            // mem = Wbt @ membf + bbt
            float es = mv_full(WBTc, reinterpret_cast<const float4*>(xbuf[p]));
            mem[tid] = es + bbt[tid];
            __syncthreads();
        } else {
            mem[tid] = outp;
            if (tid < SEQ) {
                out[2 * SEQ + t * SEQ + tid] = 0.f;
                out[2 * SEQ + SEQ * SEQ + t * SEQ + tid] = 0.f;
            }
            __syncthreads();
        }
    }
}

// ---------------------------------------------------------------------------
extern "C" void kernel_launch(void* const* d_in, const int* in_sizes, int n_in,
                              void* d_out, int out_size, void* d_ws, size_t ws_size,
                              hipStream_t stream)
{
    (void)in_sizes; (void)n_in; (void)out_size; (void)ws_size;
    const int*   text       = (const int*)  d_in[0];
    const float* wordvector = (const float*)d_in[1];
    const float* relvec     = (const float*)d_in[2];
    const float* entvec     = (const float*)d_in[3];
    const float* WihL = (const float*)d_in[4];  const float* WhhL = (const float*)d_in[5];
    const float* bihL = (const float*)d_in[6];  const float* bhhL = (const float*)d_in[7];
    const float* WihR = (const float*)d_in[8];  const float* WhhR = (const float*)d_in[9];
    const float* bihR = (const float*)d_in[10]; const float* bhhR = (const float*)d_in[11];
    const float* Wt   = (const float*)d_in[12]; const float* bt   = (const float*)d_in[13];
    const float* Wp   = (const float*)d_in[14]; const float* bp   = (const float*)d_in[15];
    const float* Wb   = (const float*)d_in[16]; const float* bb   = (const float*)d_in[17];
    const float* Wpl  = (const float*)d_in[18]; const float* bpl  = (const float*)d_in[19];
    const float* Wtt  = (const float*)d_in[20]; const float* btt  = (const float*)d_in[21];
    const float* Wtb  = (const float*)d_in[22]; const float* btb  = (const float*)d_in[23];
    const float* Wbt  = (const float*)d_in[24]; const float* bbt  = (const float*)d_in[25];

    float* ws = (float*)d_ws;
    size_t o = 0;
    auto take = [&](size_t n) { float* p = ws + o; o += n; return p; };
    float* XGF    = take(SEQ * G);
    float* XGB    = take(SEQ * G);
    float* WHLT   = take(D * G);
    float* WHRT   = take(D * G);
    float* WORDIN = take(SEQ * 2 * D);
    float* TW     = take(SEQ * D);
    float* BW     = take(SEQ * D);
    float* RVb    = take(NREL * D);
    float* EVb    = take(NENT * D);
    float* WTWT   = take(2 * D * D);
    float* WTRT   = take(D * D);
    float* WTMT   = take(D * D);
    float* WBWT   = take(2 * D * D);
    float* WBET   = take(D * D);
    float* WBGT   = take(D * D);
    float* WTBT   = take(D * D);
    float* WBTT   = take(D * D);
    float* M1T    = take(D * D);
    float* C1     = take(D);
    float* WREG   = take(256 * 48);      // register-tier pack (k 0..47)
    float* WLDS   = take(256 * 144);     // LDS-tier pack (k 48..191)
    float* WGL    = take(256 * 64);      // L2-tier pack (k 192..255)

    auto tr = [&](const float* in, float* outp, int rows, int cols, int stride, int off) {
        int n = rows * cols;
        k_trans<<<(n + 255) / 256, 256, 0, stream>>>(in, outp, rows, cols, stride, off);
    };
    tr(WhhL, WHLT, G, D, D, 0);          // WHLT[k*G + j] = WhhL[j][k]
    tr(WhhR, WHRT, G, D, D, 0);
    tr(Wt,  WTWT, D, 2 * D, G, 0);       // word part of Wt
    tr(Wt,  WTRT, D, D, G, 512);         // relvec part
    tr(Wt,  WTMT, D, D, G, 768);         // mem part
    tr(Wb,  WBWT, D, 2 * D, 5 * D, 0);   // word part of Wb
    tr(Wb,  WBET, D, D, 5 * D, 512);     // entvec part
    tr(Wb,  WBGT, D, D, 5 * D, 1024);    // target part (feeds M1/c1)
    tr(Wtb, WTBT, D, D, D, 0);
    tr(Wbt, WBTT, D, D, D, 0);

    k_m1<<<D, D, 0, stream>>>(WBGT, Wtt, M1T);
    k_c1<<<1, D, 0, stream>>>(WBGT, btt, C1);
    k_pack9r<<<48, 256, 0, stream>>>(Wb, WREG);
    k_pack9l<<<144, 256, 0, stream>>>(Wb, WLDS);
    k_pack9g<<<64, 256, 0, stream>>>(Wb, WGL);

    k_xg<<<SEQ, 1024, 0, stream>>>(text, wordvector, WihL, bihL, bhhL, XGF);
    k_xg<<<SEQ, 1024, 0, stream>>>(text, wordvector, WihR, bihR, bhhR, XGB);
    k_lstm<<<2, 1024, 0, stream>>>(XGF, XGB, WHLT, WHRT, WORDIN);
    k_prep2<<<SEQ + NREL + NENT, 256, 0, stream>>>(WORDIN, WTWT, WBWT, WTRT, WBET,
                                                   relvec, entvec, bt, bb,
                                                   TW, BW, RVb, EVb);
    k_main8<<<1, 256, 0, stream>>>(TW, BW, RVb, EVb, WTMT, WTBT, WBTT, M1T, C1,
                                   WREG, WLDS, WGL, Wp, bp, Wpl, bpl, btb, bbt,
                                   (float*)d_out);
}